// Round 2
// baseline (114.953 us; speedup 1.0000x reference)
//
#include <hip/hip_runtime.h>
#include <math.h>

#define NB 8192
#define DK 128
#define TI 128                         // square tile edge (rows == cols)
#define NTILES (NB / TI)               // 64
#define NBLK (NTILES * (NTILES + 1) / 2)  // 2080 upper-triangle blocks
#define JT 64                          // j-cols per LDS tile
#define NT (TI / JT)                   // 2 j-tiles per block
#define BSTRH 136                      // B LDS row stride in bf16 (272 B) -> conflict-free b128
#define NCOMB (NB / 256)               // 32 combine blocks

typedef __attribute__((ext_vector_type(8))) short short8;
typedef __attribute__((ext_vector_type(16))) float float16;

__device__ inline unsigned short f2bf(float f) {
    unsigned int x = __float_as_uint(f);
    unsigned int r = (x + 0x7fffu + ((x >> 16) & 1u)) >> 16;
    return (unsigned short)r;
}

// ---------------- normalize -> bf16, packed meta, and zero accum/ticket ---------
__global__ void norm_kernel(const float* __restrict__ emb, const int* __restrict__ labels,
                            const int* __restrict__ groups, unsigned short* __restrict__ xnb,
                            int* __restrict__ meta, float* __restrict__ accum,
                            int* __restrict__ ticket) {
    int row  = blockIdx.x * 4 + (threadIdx.x >> 6);
    int lane = threadIdx.x & 63;
    float2 v = ((const float2*)(emb + (size_t)row * DK))[lane];
    float ss = v.x * v.x + v.y * v.y;
#pragma unroll
    for (int off = 32; off; off >>= 1) ss += __shfl_xor(ss, off, 64);
    float inv = 1.0f / fmaxf(sqrtf(ss), 1e-12f);
    ushort2 o;
    o.x = f2bf(v.x * inv);
    o.y = f2bf(v.y * inv);
    ((ushort2*)(xnb + (size_t)row * DK))[lane] = o;
    if (lane == 0) meta[row] = (labels[row] << 8) | groups[row];
    if (blockIdx.x == 0 && threadIdx.x == 0) {
        accum[0] = 0.0f; accum[1] = 0.0f; ticket[0] = 0;
    }
}

// ---------------- symmetric (upper-triangle) MFMA gram + two-sided mining -------
// Encoded similarity space (same as previous kernel, proven):
//   -t = (same_label? 8:0) - s   feeds apn (row) AND apn_col (col side, symmetric)
//    v = s - 8*sl + 4*sg         feeds anc (row) AND anc_col
// C layout (verified): col = lane&31, row = (reg&3) + 8*(reg>>2) + 4*(lane>>5)
__global__ __launch_bounds__(256, 3) void mine_tri(
    const unsigned short* __restrict__ xnb, const int* __restrict__ meta,
    float* __restrict__ ap_row, float* __restrict__ an_row,
    float* __restrict__ ap_col, float* __restrict__ an_col) {
    __shared__ unsigned short Bs[2][JT * BSTRH];   // 2 x 17408 B

    // map blockIdx.x -> (ti, tj), ti <= tj  (ti-major enumeration keeps A-tile hot in L2)
    int bid = blockIdx.x;
    int ti = 0;
    while (bid >= NTILES - ti) { bid -= NTILES - ti; ti++; }
    const int tj = ti + bid;

    const int tid  = threadIdx.x;
    const int w    = tid >> 6;
    const int lane = tid & 63;
    const int half = lane >> 5;
    const int l31  = lane & 31;
    const int i0    = ti * TI;
    const int jbase = tj * TI;
    const int irow  = i0 + w * 32;

    // A fragments, full K=128 resident (8 x short8 = 64 VGPRs)
    short8 afrag[8];
#pragma unroll
    for (int ks = 0; ks < 8; ks++)
        afrag[ks] = *(const short8*)(xnb + (size_t)(irow + l31) * DK + ks * 16 + half * 8);

    int metaI[16];
    float apn[16], anc[16];
#pragma unroll
    for (int reg = 0; reg < 16; reg++) {
        int r = (reg & 3) + 8 * (reg >> 2) + 4 * half;
        metaI[reg] = meta[irow + r];
        apn[reg] = -1e9f; anc[reg] = -1e9f;
    }
    float apnC[4], ancC[4];                       // col-side accumulators, q = jt*2+ct
#pragma unroll
    for (int q = 0; q < 4; q++) { apnC[q] = -1e9f; ancC[q] = -1e9f; }

    // prologue: stage tile 0 (rows jbase .. jbase+63)
#pragma unroll
    for (int s = 0; s < 4; s++) {
        int chunk = tid + s * 256;
        int row = chunk >> 4, k4 = chunk & 15;
        *(uint4*)&Bs[0][row * BSTRH + k4 * 8] =
            *(const uint4*)(xnb + (size_t)(jbase + row) * DK + k4 * 8);
    }
    __syncthreads();

#pragma unroll
    for (int jt = 0; jt < NT; jt++) {
        const int cur = jt & 1;
        const int j0  = jbase + jt * JT;

        // prefetch next tile into registers (overlaps with compute below)
        uint4 pre[4];
        if (jt + 1 < NT) {
            const int j0n = j0 + JT;
#pragma unroll
            for (int s = 0; s < 4; s++) {
                int chunk = tid + s * 256;
                int row = chunk >> 4, k4 = chunk & 15;
                pre[s] = *(const uint4*)(xnb + (size_t)(j0n + row) * DK + k4 * 8);
            }
        }

        int mjc[2];
        mjc[0] = meta[j0 + l31];
        mjc[1] = meta[j0 + 32 + l31];

#pragma unroll
        for (int ct = 0; ct < 2; ct++) {
            float16 c;
#pragma unroll
            for (int e = 0; e < 16; e++) c[e] = 0.0f;

            const int bro = ct * 32 + l31;
#pragma unroll
            for (int ks = 0; ks < 8; ks++) {
                short8 b = *(const short8*)&Bs[cur][bro * BSTRH + ks * 16 + half * 8];
                c = __builtin_amdgcn_mfma_f32_32x32x16_bf16(afrag[ks], b, c, 0, 0, 0);
            }

            const int mj = mjc[ct];
            const int q  = jt * 2 + ct;           // compile-time (both loops unrolled)
#pragma unroll
            for (int reg = 0; reg < 16; reg++) {
                float s = c[reg];
                int x = metaI[reg] ^ mj;
                bool sl = (unsigned)x < 0x100u;   // same label
                float t8 = s - 8.0f;
                float t  = sl ? t8 : s;           // t = s - (sl?8:0)
                float negt = -t;
                apn[reg] = fmaxf(apn[reg], negt); // row-side (anchor = i)
                apnC[q]  = fmaxf(apnC[q],  negt); // col-side (anchor = j), symmetric
                bool sg = (x & 0xFFu) == 0u;      // same group
                float t4 = t + 4.0f;
                float v  = sg ? t4 : t;           // + (sg?4:0)
                anc[reg] = fmaxf(anc[reg], v);
                ancC[q]  = fmaxf(ancC[q],  v);
            }
        }

        // write prefetched tile into the other buffer
        if (jt + 1 < NT) {
#pragma unroll
            for (int s = 0; s < 4; s++) {
                int chunk = tid + s * 256;
                int row = chunk >> 4, k4 = chunk & 15;
                *(uint4*)&Bs[cur ^ 1][row * BSTRH + k4 * 8] = pre[s];
            }
        }
        __syncthreads();
    }

    // ---- row side: butterfly reduce across the 32 column-lanes, write slot tj ----
#pragma unroll
    for (int reg = 0; reg < 16; reg++) {
#pragma unroll
        for (int off = 16; off; off >>= 1) {
            apn[reg] = fmaxf(apn[reg], __shfl_xor(apn[reg], off, 64));
            anc[reg] = fmaxf(anc[reg], __shfl_xor(anc[reg], off, 64));
        }
    }
    if (l31 == 0) {
#pragma unroll
        for (int reg = 0; reg < 16; reg++) {
            int r = (reg & 3) + 8 * (reg >> 2) + 4 * half;
            size_t idx = (size_t)tj * NB + (irow + r);
            ap_row[idx] = apn[reg];
            an_row[idx] = anc[reg];
        }
    }

    // ---- col side: merge halves, cross-wave reduce via LDS, write slot ti ----
    // (safe to alias Bs: final __syncthreads above guarantees all reads done)
    float* colred = (float*)&Bs[0][0];            // [2 arr][4 wave][4 q][32 col] = 4 KB
#pragma unroll
    for (int q = 0; q < 4; q++) {
        apnC[q] = fmaxf(apnC[q], __shfl_xor(apnC[q], 32, 64));
        ancC[q] = fmaxf(ancC[q], __shfl_xor(ancC[q], 32, 64));
        if (half == 0) {
            colred[0 * 512 + w * 128 + q * 32 + l31] = apnC[q];
            colred[1 * 512 + w * 128 + q * 32 + l31] = ancC[q];
        }
    }
    __syncthreads();
    {
        int arr = tid >> 7;                       // 0: apn, 1: anc
        int e   = tid & 127;                      // q*32 + col
        float m = -1e9f;
#pragma unroll
        for (int wv = 0; wv < 4; wv++)
            m = fmaxf(m, colred[arr * 512 + wv * 128 + e]);
        size_t idx = (size_t)ti * NB + (jbase + e);
        if (arr == 0) ap_col[idx] = m;
        else          an_col[idx] = m;
    }
}

// ---------------- combine valid slots + ticketed finalize (fused) ----------------
// row i (tile ti = i>>7): row-slots s in [ti, 63], col-slots s in [0, ti] -> 65 each
__global__ void combine_kernel(const float* __restrict__ ap_row,
                               const float* __restrict__ an_row,
                               const float* __restrict__ ap_col,
                               const float* __restrict__ an_col,
                               float* __restrict__ accum, int* __restrict__ ticket,
                               float* __restrict__ out) {
    int i = blockIdx.x * 256 + threadIdx.x;
    int ti = i >> 7;                              // uniform per wave (128 = 2 waves/tile)
    float apn = -1e9f, anc = -1e9f;
    for (int s = ti; s < NTILES; s++) {
        size_t idx = (size_t)s * NB + i;
        apn = fmaxf(apn, ap_row[idx]);
        anc = fmaxf(anc, an_row[idx]);
    }
    for (int s = 0; s <= ti; s++) {
        size_t idx = (size_t)s * NB + i;
        apn = fmaxf(apn, ap_col[idx]);
        anc = fmaxf(anc, an_col[idx]);
    }
    float anS = (anc > 2.0f) ? anc - 4.0f : anc;
    // loss = anS - (8 - apn) + 0.1 ; suppressed-label values decode to loss <= 0
    float loss = anS + apn - 7.9f;
    float inc = (loss > 0.0f) ? 1.0f : 0.0f;
    float val = inc * loss;

    __shared__ float ssum[4], scnt[4];
#pragma unroll
    for (int off = 32; off; off >>= 1) {
        val += __shfl_xor(val, off, 64);
        inc += __shfl_xor(inc, off, 64);
    }
    int wid = threadIdx.x >> 6, lane = threadIdx.x & 63;
    if (lane == 0) { ssum[wid] = val; scnt[wid] = inc; }
    __syncthreads();
    if (threadIdx.x == 0) {
        float s = 0.f, c = 0.f;
#pragma unroll
        for (int wv = 0; wv < 4; wv++) { s += ssum[wv]; c += scnt[wv]; }
        atomicAdd(&accum[0], s);
        atomicAdd(&accum[1], c);
        __threadfence();                       // release: accum adds visible device-wide
        int old = atomicAdd(ticket, 1);        // device-scope
        if (old == gridDim.x - 1) {            // last block finalizes
            __threadfence();                   // acquire side
            float total = __hip_atomic_load(&accum[0], __ATOMIC_RELAXED, __HIP_MEMORY_SCOPE_AGENT);
            float cnt   = __hip_atomic_load(&accum[1], __ATOMIC_RELAXED, __HIP_MEMORY_SCOPE_AGENT);
            float r = (cnt > 0.0f) ? total / fmaxf(cnt, 1.0f) : 0.0f;
            if (isnan(r)) r = 0.0f;
            out[0] = r;
        }
    }
}

extern "C" void kernel_launch(void* const* d_in, const int* in_sizes, int n_in,
                              void* d_out, int out_size, void* d_ws, size_t ws_size,
                              hipStream_t stream) {
    const float* emb  = (const float*)d_in[0];
    const int* labels = (const int*)d_in[1];
    const int* groups = (const int*)d_in[2];
    float* out = (float*)d_out;

    unsigned short* xnb = (unsigned short*)d_ws;            // 2 MB
    int*   meta   = (int*)(xnb + (size_t)NB * DK);          // 32 KB
    float* ap_row = (float*)(meta + NB);                    // 4 x 2 MB partials
    float* an_row = ap_row + (size_t)NTILES * NB;
    float* ap_col = an_row + (size_t)NTILES * NB;
    float* an_col = ap_col + (size_t)NTILES * NB;
    float* accum  = an_col + (size_t)NTILES * NB;           // 2 floats
    int*   ticket = (int*)(accum + 2);                      // 1 int

    norm_kernel<<<NB / 4, 256, 0, stream>>>(emb, labels, groups, xnb, meta, accum, ticket);
    mine_tri<<<NBLK, 256, 0, stream>>>(xnb, meta, ap_row, an_row, ap_col, an_col);
    combine_kernel<<<NCOMB, 256, 0, stream>>>(ap_row, an_row, ap_col, an_col, accum, ticket, out);
}

// Round 3
// 100.782 us; speedup vs baseline: 1.1406x; 1.1406x over previous
//
#include <hip/hip_runtime.h>
#include <math.h>

#define NB 8192
#define DK 128
#define TI 128                         // square tile edge (rows == cols)
#define NTILES (NB / TI)               // 64
#define NBLK (NTILES * (NTILES + 1) / 2)  // 2080 upper-triangle blocks
#define JT 64                          // j-cols per LDS tile
#define NT (TI / JT)                   // 2 j-tiles per block
#define BSTRH 136                      // B LDS row stride in bf16 (272 B) -> conflict-free b128
#define NCOMB (NB / 256)               // 32 combine blocks

typedef __attribute__((ext_vector_type(8))) short short8;
typedef __attribute__((ext_vector_type(16))) float float16;

__device__ inline unsigned short f2bf(float f) {
    unsigned int x = __float_as_uint(f);
    unsigned int r = (x + 0x7fffu + ((x >> 16) & 1u)) >> 16;
    return (unsigned short)r;
}

// ---------------- normalize -> bf16, packed meta, and zero accum/ticket ---------
__global__ void norm_kernel(const float* __restrict__ emb, const int* __restrict__ labels,
                            const int* __restrict__ groups, unsigned short* __restrict__ xnb,
                            int* __restrict__ meta, float* __restrict__ accum,
                            int* __restrict__ ticket) {
    int row  = blockIdx.x * 4 + (threadIdx.x >> 6);
    int lane = threadIdx.x & 63;
    float2 v = ((const float2*)(emb + (size_t)row * DK))[lane];
    float ss = v.x * v.x + v.y * v.y;
#pragma unroll
    for (int off = 32; off; off >>= 1) ss += __shfl_xor(ss, off, 64);
    float inv = 1.0f / fmaxf(sqrtf(ss), 1e-12f);
    ushort2 o;
    o.x = f2bf(v.x * inv);
    o.y = f2bf(v.y * inv);
    ((ushort2*)(xnb + (size_t)row * DK))[lane] = o;
    if (lane == 0) meta[row] = (labels[row] << 8) | groups[row];
    if (blockIdx.x == 0 && threadIdx.x == 0) {
        accum[0] = 0.0f; accum[1] = 0.0f; ticket[0] = 0;
    }
}

// ---------------- symmetric (upper-triangle) MFMA gram + two-sided mining -------
// Encoded similarity space (proven in prior rounds):
//   -t = (same_label? 8:0) - s   feeds apn (row) AND apn_col (col side, symmetric)
//    v = s - 8*sl + 4*sg         feeds anc (row) AND anc_col
// C layout (verified): col = lane&31, row = (reg&3) + 8*(reg>>2) + 4*(lane>>5)
//
// Unified partial array part[64][NB] (float2 {apn, anc}):
//   row-side of block (ti,tj) writes (slot tj, rows of tile ti)   [slot >= rowtile]
//   col-side of block (ti,tj), ti<tj, writes (slot ti, rows of tile tj) [slot < rowtile]
//   diagonal blocks skip col-side (identical to row-side by symmetry)
// => every (slot, row) written exactly once; all 64 slots valid for every row.
__global__ __launch_bounds__(256, 3) void mine_tri(
    const unsigned short* __restrict__ xnb, const int* __restrict__ meta,
    float2* __restrict__ part) {
    __shared__ unsigned short Bs[2][JT * BSTRH];   // 2 x 17408 B

    // map blockIdx.x -> (ti, tj), ti <= tj
    int bid = blockIdx.x;
    int ti = 0;
    while (bid >= NTILES - ti) { bid -= NTILES - ti; ti++; }
    const int tj = ti + bid;

    const int tid  = threadIdx.x;
    const int w    = tid >> 6;
    const int lane = tid & 63;
    const int half = lane >> 5;
    const int l31  = lane & 31;
    const int i0    = ti * TI;
    const int jbase = tj * TI;
    const int irow  = i0 + w * 32;

    // A fragments, full K=128 resident (8 x short8 = 64 VGPRs)
    short8 afrag[8];
#pragma unroll
    for (int ks = 0; ks < 8; ks++)
        afrag[ks] = *(const short8*)(xnb + (size_t)(irow + l31) * DK + ks * 16 + half * 8);

    int metaI[16];
    float apn[16], anc[16];
#pragma unroll
    for (int reg = 0; reg < 16; reg++) {
        int r = (reg & 3) + 8 * (reg >> 2) + 4 * half;
        metaI[reg] = meta[irow + r];
        apn[reg] = -1e9f; anc[reg] = -1e9f;
    }
    float apnC[4], ancC[4];                       // col-side accumulators, q = jt*2+ct
#pragma unroll
    for (int q = 0; q < 4; q++) { apnC[q] = -1e9f; ancC[q] = -1e9f; }

    // prologue: stage tile 0 (rows jbase .. jbase+63)
#pragma unroll
    for (int s = 0; s < 4; s++) {
        int chunk = tid + s * 256;
        int row = chunk >> 4, k4 = chunk & 15;
        *(uint4*)&Bs[0][row * BSTRH + k4 * 8] =
            *(const uint4*)(xnb + (size_t)(jbase + row) * DK + k4 * 8);
    }
    __syncthreads();

#pragma unroll
    for (int jt = 0; jt < NT; jt++) {
        const int cur = jt & 1;
        const int j0  = jbase + jt * JT;

        // prefetch next tile into registers (overlaps with compute below)
        uint4 pre[4];
        if (jt + 1 < NT) {
            const int j0n = j0 + JT;
#pragma unroll
            for (int s = 0; s < 4; s++) {
                int chunk = tid + s * 256;
                int row = chunk >> 4, k4 = chunk & 15;
                pre[s] = *(const uint4*)(xnb + (size_t)(j0n + row) * DK + k4 * 8);
            }
        }

        int mjc[2];
        mjc[0] = meta[j0 + l31];
        mjc[1] = meta[j0 + 32 + l31];

#pragma unroll
        for (int ct = 0; ct < 2; ct++) {
            float16 c;
#pragma unroll
            for (int e = 0; e < 16; e++) c[e] = 0.0f;

            const int bro = ct * 32 + l31;
#pragma unroll
            for (int ks = 0; ks < 8; ks++) {
                short8 b = *(const short8*)&Bs[cur][bro * BSTRH + ks * 16 + half * 8];
                c = __builtin_amdgcn_mfma_f32_32x32x16_bf16(afrag[ks], b, c, 0, 0, 0);
            }

            const int mj = mjc[ct];
            const int q  = jt * 2 + ct;           // compile-time (both loops unrolled)
#pragma unroll
            for (int reg = 0; reg < 16; reg++) {
                float s = c[reg];
                int x = metaI[reg] ^ mj;
                bool sl = (unsigned)x < 0x100u;   // same label
                float t8 = s - 8.0f;
                float t  = sl ? t8 : s;           // t = s - (sl?8:0)
                float negt = -t;
                apn[reg] = fmaxf(apn[reg], negt); // row-side (anchor = i)
                apnC[q]  = fmaxf(apnC[q],  negt); // col-side (anchor = j), symmetric
                bool sg = (x & 0xFFu) == 0u;      // same group
                float t4 = t + 4.0f;
                float v  = sg ? t4 : t;           // + (sg?4:0)
                anc[reg] = fmaxf(anc[reg], v);
                ancC[q]  = fmaxf(ancC[q],  v);
            }
        }

        // write prefetched tile into the other buffer
        if (jt + 1 < NT) {
#pragma unroll
            for (int s = 0; s < 4; s++) {
                int chunk = tid + s * 256;
                int row = chunk >> 4, k4 = chunk & 15;
                *(uint4*)&Bs[cur ^ 1][row * BSTRH + k4 * 8] = pre[s];
            }
        }
        __syncthreads();
    }

    // ---- row side: butterfly reduce across the 32 column-lanes, write slot tj ----
#pragma unroll
    for (int reg = 0; reg < 16; reg++) {
#pragma unroll
        for (int off = 16; off; off >>= 1) {
            apn[reg] = fmaxf(apn[reg], __shfl_xor(apn[reg], off, 64));
            anc[reg] = fmaxf(anc[reg], __shfl_xor(anc[reg], off, 64));
        }
    }
    if (l31 == 0) {
#pragma unroll
        for (int reg = 0; reg < 16; reg++) {
            int r = (reg & 3) + 8 * (reg >> 2) + 4 * half;
            float2 o; o.x = apn[reg]; o.y = anc[reg];
            part[(size_t)tj * NB + (irow + r)] = o;
        }
    }

    // ---- col side: merge halves, cross-wave reduce via LDS, write slot ti ----
    // (safe to alias Bs: final __syncthreads above guarantees all reads done)
    float* colred = (float*)&Bs[0][0];            // [2 arr][4 wave][4 q][32 col] = 4 KB
#pragma unroll
    for (int q = 0; q < 4; q++) {
        apnC[q] = fmaxf(apnC[q], __shfl_xor(apnC[q], 32, 64));
        ancC[q] = fmaxf(ancC[q], __shfl_xor(ancC[q], 32, 64));
        if (half == 0) {
            colred[0 * 512 + w * 128 + q * 32 + l31] = apnC[q];
            colred[1 * 512 + w * 128 + q * 32 + l31] = ancC[q];
        }
    }
    __syncthreads();
    if (tid < 128 && ti != tj) {                  // diagonal: col-side == row-side, skip
        int e = tid;                              // q*32 + col within the 128-col tile
        float ma = -1e9f, mn = -1e9f;
#pragma unroll
        for (int wv = 0; wv < 4; wv++) {
            ma = fmaxf(ma, colred[0 * 512 + wv * 128 + e]);
            mn = fmaxf(mn, colred[1 * 512 + wv * 128 + e]);
        }
        float2 o; o.x = ma; o.y = mn;
        part[(size_t)ti * NB + (jbase + e)] = o;
    }
}

// ---------------- combine all 64 valid slots + ticketed finalize ----------------
__global__ void combine_kernel(const float2* __restrict__ part,
                               float* __restrict__ accum, int* __restrict__ ticket,
                               float* __restrict__ out) {
    int i = blockIdx.x * 256 + threadIdx.x;
    float a0 = -1e9f, a1 = -1e9f, a2 = -1e9f, a3 = -1e9f;   // apn partial maxes
    float n0 = -1e9f, n1 = -1e9f, n2 = -1e9f, n3 = -1e9f;   // anc partial maxes
#pragma unroll
    for (int s = 0; s < NTILES; s += 4) {
        float2 p0 = part[(size_t)(s + 0) * NB + i];
        float2 p1 = part[(size_t)(s + 1) * NB + i];
        float2 p2 = part[(size_t)(s + 2) * NB + i];
        float2 p3 = part[(size_t)(s + 3) * NB + i];
        a0 = fmaxf(a0, p0.x); n0 = fmaxf(n0, p0.y);
        a1 = fmaxf(a1, p1.x); n1 = fmaxf(n1, p1.y);
        a2 = fmaxf(a2, p2.x); n2 = fmaxf(n2, p2.y);
        a3 = fmaxf(a3, p3.x); n3 = fmaxf(n3, p3.y);
    }
    float apn = fmaxf(fmaxf(a0, a1), fmaxf(a2, a3));
    float anc = fmaxf(fmaxf(n0, n1), fmaxf(n2, n3));

    float anS = (anc > 2.0f) ? anc - 4.0f : anc;
    // loss = anS - (8 - apn) + 0.1 ; suppressed-label values decode to loss <= 0
    float loss = anS + apn - 7.9f;
    float inc = (loss > 0.0f) ? 1.0f : 0.0f;
    float val = inc * loss;

    __shared__ float ssum[4], scnt[4];
#pragma unroll
    for (int off = 32; off; off >>= 1) {
        val += __shfl_xor(val, off, 64);
        inc += __shfl_xor(inc, off, 64);
    }
    int wid = threadIdx.x >> 6, lane = threadIdx.x & 63;
    if (lane == 0) { ssum[wid] = val; scnt[wid] = inc; }
    __syncthreads();
    if (threadIdx.x == 0) {
        float s = 0.f, c = 0.f;
#pragma unroll
        for (int wv = 0; wv < 4; wv++) { s += ssum[wv]; c += scnt[wv]; }
        atomicAdd(&accum[0], s);
        atomicAdd(&accum[1], c);
        __threadfence();                       // release: accum adds visible device-wide
        int old = atomicAdd(ticket, 1);        // device-scope
        if (old == gridDim.x - 1) {            // last block finalizes
            __threadfence();                   // acquire side
            float total = __hip_atomic_load(&accum[0], __ATOMIC_RELAXED, __HIP_MEMORY_SCOPE_AGENT);
            float cnt   = __hip_atomic_load(&accum[1], __ATOMIC_RELAXED, __HIP_MEMORY_SCOPE_AGENT);
            float r = (cnt > 0.0f) ? total / fmaxf(cnt, 1.0f) : 0.0f;
            if (isnan(r)) r = 0.0f;
            out[0] = r;
        }
    }
}

extern "C" void kernel_launch(void* const* d_in, const int* in_sizes, int n_in,
                              void* d_out, int out_size, void* d_ws, size_t ws_size,
                              hipStream_t stream) {
    const float* emb  = (const float*)d_in[0];
    const int* labels = (const int*)d_in[1];
    const int* groups = (const int*)d_in[2];
    float* out = (float*)d_out;

    unsigned short* xnb = (unsigned short*)d_ws;            // 2 MB
    int*    meta   = (int*)(xnb + (size_t)NB * DK);         // 32 KB
    float2* part   = (float2*)(meta + NB);                  // 4 MB: [64][NB] {apn,anc}
    float*  accum  = (float*)(part + (size_t)NTILES * NB);  // 2 floats
    int*    ticket = (int*)(accum + 2);                     // 1 int

    norm_kernel<<<NB / 4, 256, 0, stream>>>(emb, labels, groups, xnb, meta, accum, ticket);
    mine_tri<<<NBLK, 256, 0, stream>>>(xnb, meta, part);
    combine_kernel<<<NCOMB, 256, 0, stream>>>(part, accum, ticket, out);
}